// Round 10
// baseline (171.378 us; speedup 1.0000x reference)
//
#include <hip/hip_runtime.h>
#include <math.h>

#define NB 1024  // batch

// ---------------------------------------------------------------------------
// K0: transpose x (B, C*H*W=3072) -> xT (3072, B), 64x64 LDS tiles
// ---------------------------------------------------------------------------
__global__ __launch_bounds__(256) void k_transpose(const float* __restrict__ x,
                                                   float* __restrict__ xT) {
  __shared__ float tile[64][65];
  const int c0 = blockIdx.x * 64;   // chw tile
  const int b0 = blockIdx.y * 64;   // batch tile
  const int tx = threadIdx.x & 63;
  const int ty = threadIdx.x >> 6;
#pragma unroll
  for (int r = 0; r < 16; ++r) {
    const int bb = r * 4 + ty;
    tile[bb][tx] = x[(size_t)(b0 + bb) * 3072 + c0 + tx];  // coalesced over chw
  }
  __syncthreads();
#pragma unroll
  for (int r = 0; r < 16; ++r) {
    const int cc = r * 4 + ty;
    xT[(size_t)(c0 + cc) * NB + b0 + tx] = tile[tx][cc];   // coalesced over b
  }
}

// ---------------------------------------------------------------------------
// K1: untied conv1 + bias + relu + 2x2 maxpool. xT (3,32,32,B) -> h1 (6,14,14,B)
//     Wave-per-pool-quadrant: block 256 = 4 waves, wave = (i,j) in 2x2 pool
//     window, lane = 2 batches (float2, 128 b/block). 4x the waves of R8
//     (24 waves/CU demand) to hide LDS/L2 latency; per-thread chain 4x shorter.
//     Grid 1568 = 196 pos x 8 bg; bg = u&7 -> each XCD owns one 128-b slice
//     (xT slice 1.6 MB, L2-resident). Pool via LDS cross-wave reduce.
// ---------------------------------------------------------------------------
__global__ __launch_bounds__(256) void k_conv1(const float* __restrict__ xT,
                                               const float* __restrict__ w1,
                                               const float* __restrict__ b1,
                                               float* __restrict__ h1) {
  const int u = blockIdx.x;              // 0..1567
  const int bg = u & 7;                  // XCD-aligned 128-batch slice
  const int pos = u >> 3;                // 0..195
  const int ph = pos / 14, pw = pos % 14;
  const int lane = threadIdx.x & 63;
  const int ij = threadIdx.x >> 6;       // wave id = pool quadrant
  const int i = ij >> 1, j = ij & 1;
  const int b = bg * 128 + lane * 2;

  // weights: chunk = o*12 + c*4 + ij (72 chunks of 25, padded to 28)
  __shared__ __align__(16) float wL[72 * 28];
  __shared__ float bL[24];
  __shared__ float2 pool[4][6][64];
  for (int t = threadIdx.x; t < 72 * 25; t += 256) {
    const int chunk = t / 25, p = t - chunk * 25;
    const int o = chunk / 12, rem = chunk - o * 12;
    const int c = rem >> 2, ii = (rem >> 1) & 1, jj = rem & 1;
    wL[chunk * 28 + p] =
        w1[((size_t)((o * 3 + c) * 28 + (2 * ph + ii)) * 28 + (2 * pw + jj)) * 25 + p];
  }
  if (threadIdx.x < 24) {
    const int o = threadIdx.x >> 2, ii = (threadIdx.x >> 1) & 1, jj = threadIdx.x & 1;
    bL[threadIdx.x] = b1[(size_t)(o * 28 + (2 * ph + ii)) * 28 + (2 * pw + jj)];
  }
  __syncthreads();

  float2 acc[6];
#pragma unroll
  for (int o = 0; o < 6; ++o) { acc[o].x = 0.f; acc[o].y = 0.f; }

  for (int c = 0; c < 3; ++c) {
    float2 xw[25];
#pragma unroll
    for (int dh = 0; dh < 5; ++dh)
#pragma unroll
      for (int dw = 0; dw < 5; ++dw)
        xw[dh * 5 + dw] = *reinterpret_cast<const float2*>(
            &xT[((size_t)(c * 32 + (2 * ph + i + dh)) * 32 + (2 * pw + j + dw)) * NB + b]);
#pragma unroll
    for (int o = 0; o < 6; ++o) {
      const float* wp = &wL[((o * 3 + c) * 4 + ij) * 28];
#pragma unroll
      for (int p = 0; p < 25; ++p) {
        const float wv = wp[p];
        acc[o].x = fmaf(xw[p].x, wv, acc[o].x);
        acc[o].y = fmaf(xw[p].y, wv, acc[o].y);
      }
    }
  }

#pragma unroll
  for (int o = 0; o < 6; ++o) {
    const float bias = bL[o * 4 + ij];
    float2 v;
    v.x = fmaxf(acc[o].x + bias, 0.f);
    v.y = fmaxf(acc[o].y + bias, 0.f);
    pool[ij][o][lane] = v;
  }
  __syncthreads();

  for (int idx = threadIdx.x; idx < 384; idx += 256) {   // 6 o x 64 lanes
    const int o = idx >> 6, l2 = idx & 63;
    float2 m = pool[0][o][l2];
    const float2 m1 = pool[1][o][l2], m2 = pool[2][o][l2], m3 = pool[3][o][l2];
    m.x = fmaxf(fmaxf(m.x, m1.x), fmaxf(m2.x, m3.x));
    m.y = fmaxf(fmaxf(m.y, m1.y), fmaxf(m2.y, m3.y));
    *reinterpret_cast<float2*>(
        &h1[((size_t)(o * 14 + ph) * 14 + pw) * NB + bg * 128 + l2 * 2]) = m;
  }
}

// ---------------------------------------------------------------------------
// K2: untied conv2 + bias + relu + 2x2 maxpool. h1 (6,14,14,B) -> h2 (16,5,5,B)
//     Same wave-per-quadrant structure. Grid 1600 = 8 og x 25 pos x 8 bg;
//     bg = u&7 (per-XCD h1 slice 0.6 MB). 2 o's per block.
// ---------------------------------------------------------------------------
__global__ __launch_bounds__(256) void k_conv2(const float* __restrict__ h1,
                                               const float* __restrict__ w2,
                                               const float* __restrict__ b2,
                                               float* __restrict__ h2) {
  const int u = blockIdx.x;              // 0..1599
  const int bg = u & 7;
  const int k = u >> 3;                  // 0..199
  const int og = k / 25;                 // 0..7 (2 o's each)
  const int pos = k % 25;
  const int ph = pos / 5, pw = pos % 5;
  const int lane = threadIdx.x & 63;
  const int ij = threadIdx.x >> 6;
  const int i = ij >> 1, j = ij & 1;
  const int b = bg * 128 + lane * 2;

  // chunk = oo*24 + c*4 + ij  (48 chunks of 25, padded to 28)
  __shared__ __align__(16) float wL[48 * 28];
  __shared__ float bL[8];
  __shared__ float2 pool[4][2][64];
  for (int t = threadIdx.x; t < 48 * 25; t += 256) {
    const int chunk = t / 25, p = t - chunk * 25;
    const int oo = chunk / 24, rem = chunk - oo * 24;
    const int c = rem >> 2, ii = (rem >> 1) & 1, jj = rem & 1;
    const int o = og * 2 + oo;
    wL[chunk * 28 + p] =
        w2[((size_t)((o * 6 + c) * 10 + (2 * ph + ii)) * 10 + (2 * pw + jj)) * 25 + p];
  }
  if (threadIdx.x < 8) {
    const int oo = threadIdx.x >> 2, ii = (threadIdx.x >> 1) & 1, jj = threadIdx.x & 1;
    const int o = og * 2 + oo;
    bL[threadIdx.x] = b2[(size_t)(o * 10 + (2 * ph + ii)) * 10 + (2 * pw + jj)];
  }
  __syncthreads();

  float2 acc[2];
  acc[0].x = acc[0].y = acc[1].x = acc[1].y = 0.f;

  for (int c = 0; c < 6; ++c) {
    float2 xw[25];
#pragma unroll
    for (int dh = 0; dh < 5; ++dh)
#pragma unroll
      for (int dw = 0; dw < 5; ++dw)
        xw[dh * 5 + dw] = *reinterpret_cast<const float2*>(
            &h1[((size_t)(c * 14 + (2 * ph + i + dh)) * 14 + (2 * pw + j + dw)) * NB + b]);
#pragma unroll
    for (int oo = 0; oo < 2; ++oo) {
      const float* wp = &wL[((oo * 6 + c) * 4 + ij) * 28];
#pragma unroll
      for (int p = 0; p < 25; ++p) {
        const float wv = wp[p];
        acc[oo].x = fmaf(xw[p].x, wv, acc[oo].x);
        acc[oo].y = fmaf(xw[p].y, wv, acc[oo].y);
      }
    }
  }

#pragma unroll
  for (int oo = 0; oo < 2; ++oo) {
    const float bias = bL[oo * 4 + ij];
    float2 v;
    v.x = fmaxf(acc[oo].x + bias, 0.f);
    v.y = fmaxf(acc[oo].y + bias, 0.f);
    pool[ij][oo][lane] = v;
  }
  __syncthreads();

  if (threadIdx.x < 128) {               // 2 o x 64 lanes
    const int oo = threadIdx.x >> 6, l2 = threadIdx.x & 63;
    const int o = og * 2 + oo;
    float2 m = pool[0][oo][l2];
    const float2 m1 = pool[1][oo][l2], m2 = pool[2][oo][l2], m3 = pool[3][oo][l2];
    m.x = fmaxf(fmaxf(m.x, m1.x), fmaxf(m2.x, m3.x));
    m.y = fmaxf(fmaxf(m.y, m1.y), fmaxf(m2.y, m3.y));
    *reinterpret_cast<float2*>(
        &h2[((size_t)(o * 5 + ph) * 5 + pw) * NB + bg * 128 + l2 * 2]) = m;
  }
}

// ---------------------------------------------------------------------------
// K3: conv3 == GEMM k=400, split-K: block 256 = 4 ksegs x 64 lanes, 2 b/lane,
//     2 o's per block; LDS reduce over ksegs. Grid 480 = 60 opairs x 8 bg.
// ---------------------------------------------------------------------------
__global__ __launch_bounds__(256) void k_conv3(const float* __restrict__ h2,
                                               const float* __restrict__ w3,
                                               const float* __restrict__ b3,
                                               float* __restrict__ h3) {
  const int u = blockIdx.x;              // 0..479
  const int bg = u & 7;
  const int o = (u >> 3) * 2;            // 0,2,..,118
  const int lane = threadIdx.x & 63;
  const int kseg = threadIdx.x >> 6;     // 0..3
  const int b = bg * 128 + lane * 2;

  __shared__ __align__(16) float wL[2][400];
  __shared__ float2 kbuf[4][2][64];
  for (int t = threadIdx.x; t < 800; t += 256) {
    const int oo = t / 400, p = t - oo * 400;
    wL[oo][p] = w3[(size_t)(o + oo) * 400 + p];
  }
  __syncthreads();

  float2 a0 = {0.f, 0.f}, a1 = {0.f, 0.f};
  const int k0 = kseg * 100;
#pragma unroll 4
  for (int k = k0; k < k0 + 100; ++k) {
    const float2 xv = *reinterpret_cast<const float2*>(&h2[(size_t)k * NB + b]);
    const float w0 = wL[0][k], w1v = wL[1][k];
    a0.x = fmaf(xv.x, w0, a0.x);  a0.y = fmaf(xv.y, w0, a0.y);
    a1.x = fmaf(xv.x, w1v, a1.x); a1.y = fmaf(xv.y, w1v, a1.y);
  }
  kbuf[kseg][0][lane] = a0;
  kbuf[kseg][1][lane] = a1;
  __syncthreads();

  if (threadIdx.x < 128) {               // 2 o x 64 lanes
    const int oo = threadIdx.x >> 6, l2 = threadIdx.x & 63;
    const float2 s0 = kbuf[0][oo][l2], s1 = kbuf[1][oo][l2];
    const float2 s2 = kbuf[2][oo][l2], s3 = kbuf[3][oo][l2];
    const float bias = b3[o + oo];
    float2 r;
    r.x = fmaxf((s0.x + s1.x) + (s2.x + s3.x) + bias, 0.f);
    r.y = fmaxf((s0.y + s1.y) + (s2.y + s3.y) + bias, 0.f);
    *reinterpret_cast<float2*>(&h3[(size_t)(o + oo) * NB + bg * 128 + l2 * 2]) = r;
  }
}

// ---------------------------------------------------------------------------
// K4: fused FC tail. Block = 16 batches (grid 64). Stage h3[120][16] in LDS,
//     fc2+relu into h4L[84][16], then fc3 -> out.
// ---------------------------------------------------------------------------
__global__ __launch_bounds__(256) void k_fctail(const float* __restrict__ h3,
                                                const float* __restrict__ fc2w,
                                                const float* __restrict__ fc2b,
                                                const float* __restrict__ fc3w,
                                                const float* __restrict__ fc3b,
                                                float* __restrict__ out) {
  const int b0 = blockIdx.x * 16;
  const int tid = threadIdx.x;
  __shared__ float h3L[120 * 16];
  __shared__ float h4L[84 * 16];

  for (int t = tid; t < 120 * 16; t += 256) {
    const int k = t >> 4, bb = t & 15;
    h3L[t] = h3[(size_t)k * NB + b0 + bb];
  }
  __syncthreads();

  const int bb = tid & 15;
  {
    const int jbase = tid >> 4;          // 0..15
#pragma unroll
    for (int jr = 0; jr < 6; ++jr) {     // 16*6 = 96 >= 84
      const int j = jbase + jr * 16;
      if (j < 84) {
        const float* __restrict__ wp = fc2w + (size_t)j * 120;
        float a0 = 0.f, a1 = 0.f;
#pragma unroll
        for (int k = 0; k < 120; k += 2) {
          a0 = fmaf(h3L[(k + 0) * 16 + bb], wp[k + 0], a0);
          a1 = fmaf(h3L[(k + 1) * 16 + bb], wp[k + 1], a1);
        }
        h4L[j * 16 + bb] = fmaxf(a0 + a1 + fc2b[j], 0.f);
      }
    }
  }
  __syncthreads();

  if (tid < 160) {
    const int i = tid >> 4;              // 0..9
    const float* __restrict__ wp = fc3w + (size_t)i * 84;
    float a0 = 0.f, a1 = 0.f;
#pragma unroll
    for (int j = 0; j < 84; j += 2) {
      a0 = fmaf(h4L[(j + 0) * 16 + bb], wp[j + 0], a0);
      a1 = fmaf(h4L[(j + 1) * 16 + bb], wp[j + 1], a1);
    }
    out[(size_t)(b0 + bb) * 10 + i] = a0 + a1 + fc3b[i];
  }
}

// ---------------------------------------------------------------------------
extern "C" void kernel_launch(void* const* d_in, const int* in_sizes, int n_in,
                              void* d_out, int out_size, void* d_ws, size_t ws_size,
                              hipStream_t stream) {
  const float* x    = (const float*)d_in[0];
  const float* w1   = (const float*)d_in[1];
  const float* b1   = (const float*)d_in[2];
  const float* w2   = (const float*)d_in[3];
  const float* b2   = (const float*)d_in[4];
  const float* w3   = (const float*)d_in[5];
  const float* b3   = (const float*)d_in[6];
  const float* fc2w = (const float*)d_in[7];
  const float* fc2b = (const float*)d_in[8];
  const float* fc3w = (const float*)d_in[9];
  const float* fc3b = (const float*)d_in[10];
  float* out = (float*)d_out;

  float* ws = (float*)d_ws;
  float* xT = ws;                         // 3*32*32*1024  = 3,145,728 f
  float* h1 = xT + 3145728;               // 6*14*14*1024  = 1,204,224 f
  float* h2 = h1 + 1204224;               // 16*5*5*1024   =   409,600 f
  float* h3 = h2 + 409600;                // 120*1024      =   122,880 f  (~19 MB)

  k_transpose<<<dim3(48, 16), 256, 0, stream>>>(x, xT);
  k_conv1<<<dim3(1568), 256, 0, stream>>>(xT, w1, b1, h1);
  k_conv2<<<dim3(1600), 256, 0, stream>>>(h1, w2, b2, h2);
  k_conv3<<<dim3(480), 256, 0, stream>>>(h2, w3, b3, h3);
  k_fctail<<<dim3(64), 256, 0, stream>>>(h3, fc2w, fc2b, fc3w, fc3b, out);
}